// Round 6
// baseline (468.264 us; speedup 1.0000x reference)
//
#include <hip/hip_runtime.h>

// LRU forward, MI355X/gfx950.
// Pipeline: prep (4 small kernels) -> GEMM1 (Bu) -> chunked scan -> GEMM2.
// R2: XCD-compact swizzle (FETCH 299->115MB).
// R3: double-buffered LDS pipeline, 1 barrier/iter (121->112us/GEMM).
// R4: FAILED - A global->VGPR consumed same-iter = mid-iter vmcnt stall.
// R5: fused prep + vectorized scans were ~11us WORSE -> reverted here.
// R6: A-frags global->VGPR prefetched ONE ITERATION AHEAD (issued next to the
//     B staging; both drained by the next iter's barrier vmcnt(0) after a
//     full compute phase). LDS traffic 48->24KB/block-iter, LDS 32->16KB.

typedef __bf16 bf16x8 __attribute__((ext_vector_type(8)));
typedef float floatx4 __attribute__((ext_vector_type(4)));

__device__ __forceinline__ unsigned short f2bf(float f) {
  unsigned u = __float_as_uint(f);
  u += 0x7fffu + ((u >> 16) & 1u);   // RNE; inputs are finite
  return (unsigned short)(u >> 16);
}
__device__ __forceinline__ float bf2f(unsigned short s) {
  return __uint_as_float(((unsigned)s) << 16);
}

// ---------------- prep kernels ----------------

__global__ void prep_params(const float* __restrict__ nu_log,
                            const float* __restrict__ theta_log,
                            float* __restrict__ lam,    // [2048] re|im
                            float* __restrict__ lamL,   // [2048] lambda^128 re|im
                            float* __restrict__ gamma)  // [1024]
{
  int h = blockIdx.x * 256 + threadIdx.x;   // exactly 1024
  float nu = expf(nu_log[h]);
  float th = expf(theta_log[h]);
  float r = expf(-nu);
  lam[h]        = r * cosf(th);
  lam[1024 + h] = r * sinf(th);
  float rL = expf(-128.0f * nu);
  lamL[h]        = rL * cosf(128.0f * th);
  lamL[1024 + h] = rL * sinf(128.0f * th);
  gamma[h] = sqrtf(1.0f - expf(-2.0f * nu) + 1e-5f);
}

__global__ void prep_B(const float* __restrict__ B_re, const float* __restrict__ B_im,
                       const float* __restrict__ gamma, unsigned short* __restrict__ Bcat)
{
  int tid = blockIdx.x * 256 + threadIdx.x;  // 2048*1024
  int n = tid >> 10;
  int d = tid & 1023;
  int h = n & 1023;
  float v = (n < 1024 ? B_re[h * 1024 + d] : B_im[h * 1024 + d]) * gamma[h];
  Bcat[tid] = f2bf(v);
}

__global__ void prep_C(const float* __restrict__ C_re, const float* __restrict__ C_im,
                       unsigned short* __restrict__ Ccat)
{
  int tid = blockIdx.x * 256 + threadIdx.x;  // 1024*2048
  int d = tid >> 11;
  int k = tid & 2047;
  float v = (k < 1024) ? C_re[d * 1024 + k] : -C_im[d * 1024 + (k - 1024)];
  Ccat[tid] = f2bf(v);
}

__global__ void conv_inputs(const float* __restrict__ in, unsigned short* __restrict__ outb)
{
  int tid = blockIdx.x * 256 + threadIdx.x;  // 16.7M/4
  float4 v = ((const float4*)in)[tid];
  unsigned lo = (unsigned)f2bf(v.x) | ((unsigned)f2bf(v.y) << 16);
  unsigned hi = (unsigned)f2bf(v.z) | ((unsigned)f2bf(v.w) << 16);
  ((uint2*)outb)[tid] = make_uint2(lo, hi);
}

// ---------------- GEMM (A: [M,K] k-contig, Bt: [N,K] k-contig) ----------------
// 128x128 tile, BK=32, 4 waves (2x2), 16x mfma_f32_16x16x32_bf16 per wave/iter.
// B double-buffered through LDS (2x8KB) with global_load_lds. A-fragments
// loaded global->VGPR, PREFETCHED one iteration ahead (issued with the B
// staging; the next iter's barrier vmcnt(0) drains both after a full compute
// phase - this is the fix for R4's same-iter consumption stall).
// XCD-compact swizzle: xcd=id&7 owns m-tiles [xcd*16,(xcd+1)*16) x all
// n-tiles, m-fastest.
// B LDS: row r (64B) holds its four 16B k-chunks at positions p storing
// logical chunk p ^ ((r>>1)&3) (bank spread; keeps global_load_lds contiguity).

#define GEMM_STEP(KT, CUR, NXT, ACUR, ANEXT)                                     \
  {                                                                              \
    __syncthreads();                                                             \
    if ((KT) + 32 < K) {                                                         \
      const int ko = (KT) + 32;                                                  \
      __builtin_amdgcn_global_load_lds(                                          \
          (const __attribute__((address_space(1))) void*)(gB0 + ko),             \
          (__attribute__((address_space(3))) void*)&Bs[NXT][lofs0], 16, 0, 0);   \
      __builtin_amdgcn_global_load_lds(                                          \
          (const __attribute__((address_space(1))) void*)(gB1 + ko),             \
          (__attribute__((address_space(3))) void*)&Bs[NXT][lofs1], 16, 0, 0);   \
      _Pragma("unroll")                                                          \
      for (int i = 0; i < 4; ++i)                                                \
        ANEXT[i] = *reinterpret_cast<const bf16x8*>(gAf + (size_t)(i * 16) * K + ko); \
    }                                                                            \
    bf16x8 bfrag[4];                                                             \
    _Pragma("unroll")                                                            \
    for (int j = 0; j < 4; ++j) {                                                \
      const int r = wn * 64 + j * 16 + lm;                                       \
      bfrag[j] = *reinterpret_cast<const bf16x8*>(                               \
          &Bs[CUR][r * 32 + (q ^ ((r >> 1) & 3)) * 8]);                          \
    }                                                                            \
    _Pragma("unroll")                                                            \
    for (int i = 0; i < 4; ++i)                                                  \
      _Pragma("unroll")                                                          \
      for (int j = 0; j < 4; ++j)                                                \
        acc[i][j] = __builtin_amdgcn_mfma_f32_16x16x32_bf16(ACUR[i], bfrag[j],   \
                                                            acc[i][j], 0, 0, 0); \
  }

template <int EPI>
__global__ __launch_bounds__(256) void gemm_bt_kernel(
    const unsigned short* __restrict__ A,
    const unsigned short* __restrict__ Bt,
    void* __restrict__ Cout,
    int M, int N, int K,
    const float* __restrict__ skip_in,
    const float* __restrict__ skip_w)
{
  __shared__ unsigned short Bs[2][128 * 32];

  const int tid  = threadIdx.x;
  const int lane = tid & 63;
  const int wave = tid >> 6;
  const int wm = wave >> 1;
  const int wn = wave & 1;

  // XCD-compact tile assignment (M/128 == 128 assumed: 8 XCDs x 16 m-tiles)
  const int flat    = blockIdx.x;
  const int xcd     = flat & 7;
  const int local   = flat >> 3;
  const int m_tile  = xcd * 16 + (local & 15);
  const int n_tile  = local >> 4;
  const int m0 = m_tile * 128;
  const int n0 = n_tile * 128;

  const int ldr = lane >> 2;   // 0..15: row within a 16-row staging group
  const int pos = lane & 3;    // 16B chunk position within the 64B row
  const int lm  = lane & 15;   // fragment row (A: m, B: n)
  const int q   = lane >> 4;   // fragment k-chunk (k = q*8 + j)

  // B staging geometry (two rows per thread)
  const int r0 = wave * 32 + ldr;        // rows r0 and r0+16
  const int ca0 = pos ^ ((r0 >> 1) & 3);
  const int r1 = r0 + 16;
  const int ca1 = pos ^ ((r1 >> 1) & 3);
  const unsigned short* gB0 = Bt + (size_t)(n0 + r0) * K + ca0 * 8;
  const unsigned short* gB1 = Bt + (size_t)(n0 + r1) * K + ca1 * 8;
  const int lofs0 = r0 * 32 + pos * 8;
  const int lofs1 = r1 * 32 + pos * 8;

  // A direct-fragment base: lane reads rows m0 + wm*64 + i*16 + lm, 16B at k.
  // Wave covers 16 full 64B lines per load instr (4 q-lanes per line).
  const unsigned short* gAf = A + (size_t)(m0 + wm * 64 + lm) * K + q * 8;

  floatx4 acc[4][4];
#pragma unroll
  for (int i = 0; i < 4; ++i)
#pragma unroll
    for (int j = 0; j < 4; ++j)
      acc[i][j] = (floatx4){0.f, 0.f, 0.f, 0.f};

  // Preamble: stage B tile 0 into buffer 0; load A frags for tile 0.
  __builtin_amdgcn_global_load_lds(
      (const __attribute__((address_space(1))) void*)gB0,
      (__attribute__((address_space(3))) void*)&Bs[0][lofs0], 16, 0, 0);
  __builtin_amdgcn_global_load_lds(
      (const __attribute__((address_space(1))) void*)gB1,
      (__attribute__((address_space(3))) void*)&Bs[0][lofs1], 16, 0, 0);
  bf16x8 a0[4], a1[4];
#pragma unroll
  for (int i = 0; i < 4; ++i)
    a0[i] = *reinterpret_cast<const bf16x8*>(gAf + (size_t)(i * 16) * K);

  // Main loop, manually unrolled x2 for buffer/register ping-pong.
  for (int kt = 0; kt < K; kt += 64) {
    GEMM_STEP(kt,      0, 1, a0, a1);
    GEMM_STEP(kt + 32, 1, 0, a1, a0);
  }

  // Epilogue. C/D layout: col = lane&15, row = (lane>>4)*4 + reg.
#pragma unroll
  for (int i = 0; i < 4; ++i) {
#pragma unroll
    for (int j = 0; j < 4; ++j) {
      const int row0 = m0 + wm * 64 + i * 16 + q * 4;
      const int col  = n0 + wn * 64 + j * 16 + lm;
#pragma unroll
      for (int r = 0; r < 4; ++r) {
        const size_t idx = (size_t)(row0 + r) * N + col;
        if (EPI == 0) {
          ((unsigned short*)Cout)[idx] = f2bf(acc[i][j][r]);
        } else {
          ((float*)Cout)[idx] = acc[i][j][r] + skip_in[idx] * skip_w[col];
        }
      }
    }
  }
}

// ---------------- chunked scan over T ----------------
// Bu layout: [(b*4096 + t) * 2048 + h] re-plane (h<1024), +1024 im-plane.
// tid = b*32768 + c*1024 + h  (B=4, C=32 chunks of L=128, H=1024)

__global__ void scan_finals(const unsigned short* __restrict__ Bu,
                            const float* __restrict__ lam,
                            float2* __restrict__ finals)
{
  int tid = blockIdx.x * 256 + threadIdx.x;
  int h = tid & 1023, c = (tid >> 10) & 31, b = tid >> 15;
  float lre = lam[h], lim = lam[1024 + h];
  const unsigned short* p = Bu + ((size_t)(b * 4096 + c * 128) * 2048) + h;
  float yre = 0.f, yim = 0.f;
#pragma unroll 4
  for (int t = 0; t < 128; ++t) {
    float ure = bf2f(p[0]);
    float uim = bf2f(p[1024]);
    float nre = fmaf(lre, yre, fmaf(-lim, yim, ure));
    float nim = fmaf(lre, yim, fmaf(lim, yre, uim));
    yre = nre; yim = nim;
    p += 2048;
  }
  finals[tid] = make_float2(yre, yim);
}

__global__ void scan_carries(const float2* __restrict__ finals,
                             const float* __restrict__ lamL,
                             float2* __restrict__ carry)
{
  int tid = blockIdx.x * 256 + threadIdx.x;  // 4096 = B*H
  int h = tid & 1023, b = tid >> 10;
  float Lre = lamL[h], Lim = lamL[1024 + h];
  float Hre = 0.f, Him = 0.f;
  for (int c = 0; c < 32; ++c) {
    size_t i = ((size_t)(b * 32 + c) << 10) + h;
    carry[i] = make_float2(Hre, Him);   // carry INTO chunk c (H_{c-1})
    float2 f = finals[i];
    float nre = fmaf(Lre, Hre, fmaf(-Lim, Him, f.x));
    float nim = fmaf(Lre, Him, fmaf(Lim, Hre, f.y));
    Hre = nre; Him = nim;
  }
}

__global__ void scan_apply(const float* __restrict__ lam,
                           const float2* __restrict__ carry,
                           unsigned short* __restrict__ Bu)  // in-place -> hs
{
  int tid = blockIdx.x * 256 + threadIdx.x;
  int h = tid & 1023, c = (tid >> 10) & 31, b = tid >> 15;
  float lre = lam[h], lim = lam[1024 + h];
  float2 cv = carry[tid];
  float yre = cv.x, yim = cv.y;
  unsigned short* p = Bu + ((size_t)(b * 4096 + c * 128) * 2048) + h;
#pragma unroll 4
  for (int t = 0; t < 128; ++t) {
    float ure = bf2f(p[0]);
    float uim = bf2f(p[1024]);
    float nre = fmaf(lre, yre, fmaf(-lim, yim, ure));
    float nim = fmaf(lre, yim, fmaf(lim, yre, uim));
    yre = nre; yim = nim;
    p[0]    = f2bf(yre);
    p[1024] = f2bf(yim);
    p += 2048;
  }
}

// ---------------- launch ----------------

extern "C" void kernel_launch(void* const* d_in, const int* in_sizes, int n_in,
                              void* d_out, int out_size, void* d_ws, size_t ws_size,
                              hipStream_t stream)
{
  const float* inputs    = (const float*)d_in[0];
  const float* nu_log    = (const float*)d_in[1];
  const float* theta_log = (const float*)d_in[2];
  const float* B_re      = (const float*)d_in[3];
  const float* B_im      = (const float*)d_in[4];
  const float* C_re      = (const float*)d_in[5];
  const float* C_im      = (const float*)d_in[6];
  const float* D_skip    = (const float*)d_in[7];
  float* out = (float*)d_out;

  char* ws = (char*)d_ws;
  float* lam   = (float*)ws;            // 2048 f32
  float* lamL  = lam + 2048;            // 2048 f32
  float* gamma = lamL + 2048;           // 1024 f32
  unsigned short* inp_bf = (unsigned short*)(ws + (1 << 16));       // 16384x1024 bf16
  unsigned short* Bcat   = inp_bf + (size_t)16384 * 1024;           // 2048x1024
  unsigned short* Ccat   = Bcat   + (size_t)2048 * 1024;            // 1024x2048
  unsigned short* Bu     = Ccat   + (size_t)1024 * 2048;            // 16384x2048 (re|im), becomes hs in place
  float2* finals = (float2*)(Bu + (size_t)16384 * 2048);            // 131072
  float2* carry  = finals + 131072;                                 // 131072
  // total ws use ~111 MB

  prep_params<<<4,    256, 0, stream>>>(nu_log, theta_log, lam, lamL, gamma);
  prep_B     <<<8192, 256, 0, stream>>>(B_re, B_im, gamma, Bcat);
  prep_C     <<<8192, 256, 0, stream>>>(C_re, C_im, Ccat);
  conv_inputs<<<16384,256, 0, stream>>>(inputs, inp_bf);

  // GEMM1: Bu[bt, n] = inputs @ Bcat^T   (M=16384, N=2048, K=1024)
  gemm_bt_kernel<0><<<2048, 256, 0, stream>>>(
      inp_bf, Bcat, Bu, 16384, 2048, 1024, nullptr, nullptr);

  scan_finals <<<512, 256, 0, stream>>>(Bu, lam, finals);
  scan_carries<<<16,  256, 0, stream>>>(finals, lamL, carry);
  scan_apply  <<<512, 256, 0, stream>>>(lam, carry, Bu);   // Bu -> hs in place

  // GEMM2: out[bt, d] = hs @ Ccat^T + inputs * D_skip  (M=16384, N=1024, K=2048)
  gemm_bt_kernel<1><<<1024, 256, 0, stream>>>(
      Bu, Ccat, out, 16384, 1024, 2048, inputs, D_skip);
}